// Round 12
// baseline (3243.479 us; speedup 1.0000x reference)
//
#include <hip/hip_runtime.h>

#define NB 16
#define NN 307
#define NI 11

typedef __attribute__((ext_vector_type(8))) short bf16x8;
typedef __attribute__((ext_vector_type(4))) short bf16x4;
typedef __attribute__((ext_vector_type(4))) float f32x4;

// ws offsets in FLOAT units
#define OFF_ABF    0u          // 320x320 bf16 = 51200 fl
#define OFF_AGCWT  51200u      // 307*64*128 bf16 = 1257472 fl
#define OFF_AGCB   1308672u    // 307*64 f32 -> pad 20480
#define OFF_WT     1329152u    // 4096*64 bf16 = 131072 fl (seg-swizzled)
#define OFF_H      1460224u    // 16*307*64 = 314368 fl
#define OFF_Z      1774592u
#define OFF_KZ     2088960u
#define OFF_ACCZ   2403328u
#define OFF_XBF    2717696u    // 320*16*64 bf16 = 163840 fl
#define OFF_XGBF   2881536u
#define OFF_WGINT  3045376u    // 64*64 bf16 = 2048 fl
#define OFF_KHALL  3209216u    // 44 * 314368 f32 ; end ~68 MB

#define STG_STRIDE 314368u

__device__ __forceinline__ float tanh_fast(float x){
    float e = __expf(2.0f * x);
    return 1.0f - 2.0f * __builtin_amdgcn_rcpf(e + 1.0f);
}
__device__ __forceinline__ unsigned short f2bf(float f){
    unsigned u = __builtin_bit_cast(unsigned, f);
    unsigned r = u + 0x7FFFu + ((u >> 16) & 1u);
    return (unsigned short)(r >> 16);
}

// ---------- precompute ----------

__global__ void kA(const float* __restrict__ gE, unsigned short* __restrict__ Abf){
    int n = blockIdx.x;            // grid 320, 64 threads
    int lane = threadIdx.x;
    if (n >= NN){
#pragma unroll
        for (int ii = 0; ii < 5; ii++) Abf[n*320 + lane + 64*ii] = 0;
        return;
    }
    float en[8];
#pragma unroll
    for (int d = 0; d < 8; d++) en[d] = gE[n*8 + d];
    float vals[5];
    float mx = -1e30f;
#pragma unroll
    for (int ii = 0; ii < 5; ii++){
        int m = lane + 64*ii;
        float v = -1e30f;
        if (m < NN){
            float a = 0.f;
#pragma unroll
            for (int d = 0; d < 8; d++) a += en[d] * gE[m*8 + d];
            v = fmaxf(a, 0.f);
        }
        vals[ii] = v;
        mx = fmaxf(mx, v);
    }
#pragma unroll
    for (int off = 32; off >= 1; off >>= 1) mx = fmaxf(mx, __shfl_xor(mx, off, 64));
    float s = 0.f;
#pragma unroll
    for (int ii = 0; ii < 5; ii++){
        int m = lane + 64*ii;
        if (m < NN){ vals[ii] = __expf(vals[ii] - mx); s += vals[ii]; }
    }
#pragma unroll
    for (int off = 32; off >= 1; off >>= 1) s += __shfl_xor(s, off, 64);
    float inv = 1.f / s;
#pragma unroll
    for (int ii = 0; ii < 5; ii++){
        int m = lane + 64*ii;
        unsigned short v = 0;
        if (m < NN) v = f2bf(vals[ii] * inv);
        Abf[n*320 + m] = v;
    }
}

__global__ __launch_bounds__(256) void kAgcWT(const float* __restrict__ gE,
                                              const float* __restrict__ gWpool,
                                              unsigned short* __restrict__ agcWt){
    __shared__ float t[128*65];
    int tid = threadIdx.x;
    int n = blockIdx.x;            // grid 307
    float ge[8];
#pragma unroll
    for (int d = 0; d < 8; d++) ge[d] = gE[n*8 + d];
    for (int it = 0; it < 32; it++){
        int e = it*256 + tid;
        int o = e & 63, i = (e >> 6) & 63, kk = e >> 12;
        float acc = 0.f;
#pragma unroll
        for (int d = 0; d < 8; d++) acc += ge[d] * gWpool[((size_t)(d*2 + kk)*64 + i)*64 + o];
        t[(kk*64 + i)*65 + o] = acc;
    }
    __syncthreads();
    for (int it = 0; it < 32; it++){
        int e = it*256 + tid;
        int k = e & 127, o = e >> 7;
        agcWt[((size_t)n*64 + o)*128 + k] = f2bf(t[k*65 + o]);
    }
}

__global__ void kAgcB(const float* __restrict__ gE, const float* __restrict__ gbpool,
                      float* __restrict__ agcb){
    int gid = blockIdx.x*256 + threadIdx.x;
    if (gid >= NN*64) return;
    int o = gid & 63;
    int n = gid >> 6;
    float acc = 0.f;
#pragma unroll
    for (int d = 0; d < 8; d++) acc += gE[n*8 + d] * gbpool[d*64 + o];
    agcb[gid] = acc;
}

// Wt_sw[col][seg'] bf16 : transpose of WgOut with 16B-seg swizzle seg' = seg ^ (col&7)
__global__ __launch_bounds__(256) void kWt(const float* __restrict__ WgOut,
                                           unsigned short* __restrict__ Wt_sw){
    __shared__ float t[64*65];
    int tid = threadIdx.x;
    int c0 = blockIdx.x*64;        // grid 64
    for (int it = 0; it < 16; it++){
        int e = it*256 + tid;
        int k = e >> 6, c = e & 63;
        t[k*65 + c] = WgOut[(size_t)k*4096 + c0 + c];
    }
    __syncthreads();
    for (int it = 0; it < 16; it++){
        int e = it*256 + tid;
        int c = e >> 6, k = e & 63;
        int ks = ((((k >> 3) ^ (c & 7)) << 3) | (k & 7));
        Wt_sw[(size_t)(c0 + c)*64 + ks] = f2bf(t[k*65 + c]);
    }
}

// WgInT[c][k] = bf16(WgIn[k][c])
__global__ void kWgInT(const float* __restrict__ WgIn, unsigned short* __restrict__ WgInT){
    int gid = blockIdx.x*256 + threadIdx.x;   // 4096
    int c = gid >> 6, k = gid & 63;
    WgInT[gid] = f2bf(WgIn[k*64 + c]);
}

__global__ void kInit(const float* __restrict__ ca,
                      const float* __restrict__ hW, const float* __restrict__ hb,
                      const float* __restrict__ zW, const float* __restrict__ zb,
                      float* __restrict__ h, float* __restrict__ z){
    int gid = blockIdx.x*256 + threadIdx.x;   // exactly 314368
    int t = gid & 63;
    int bn = gid >> 6;
    float x0 = ca[bn*NI*2 + 0];
    float x1 = ca[bn*NI*2 + 1];
    h[gid] = x0*hW[t] + x1*hW[64 + t] + hb[t];
    z[gid] = x0*zW[t] + x1*zW[64 + t] + zb[t];
}

// ---------- KH: full h-ODE, 2 (b,n)-rows per wave (halves weight traffic) ----------
// grid 614 (614*4 waves *2 rows = 4912); fp32, per-row op order identical to R10.
__global__ __launch_bounds__(256) void KH(
    const float* __restrict__ h0, float* __restrict__ khAll,
    const float* __restrict__ Cb, const float* __restrict__ Cc, const float* __restrict__ Cd,
    const float* __restrict__ WfIn, const float* __restrict__ fbIn,
    const float* __restrict__ WfMid, const float* __restrict__ fbMid,
    const float* __restrict__ WfOut, const float* __restrict__ fbOut)
{
    __shared__ float4 bufA[4][2][16];
    __shared__ float4 bufB[4][2][16];
    int tid = threadIdx.x;
    int wv = tid >> 6;
    int lane = tid & 63;
    int bn0 = (blockIdx.x*4 + wv)*2;
    int base0 = bn0*64 + lane;

    float hv0 = h0[base0];
    float hv1 = h0[base0 + 64];
    float acch0 = 0.f, khp0 = 0.f, acch1 = 0.f, khp1 = 0.f;

#pragma unroll 1
    for (int stage = 0; stage < 44; stage++){
        int step = stage >> 2, s = stage & 3;
        float acoef = (s == 0) ? 0.f : (s == 3 ? 1.f : 0.5f);
        int idx; float frac;
        if (s == 0)        { idx = step;     frac = 0.f;  }
        else if (s < 3)    { idx = step;     frac = 0.5f; }
        else if (step < 10){ idx = step + 1; frac = 0.f;  }
        else               { idx = 10;       frac = 1.f;  }

        ((float*)&bufA[wv][0][0])[lane] = hv0 + acoef*khp0;
        ((float*)&bufA[wv][1][0])[lane] = hv1 + acoef*khp1;

        // layer 1
        float a0 = fbIn[lane], a1 = 0.f, a2 = 0.f, a3 = 0.f;
        float e0 = fbIn[lane], e1 = 0.f, e2 = 0.f, e3 = 0.f;
#pragma unroll
        for (int k4 = 0; k4 < 16; k4 += 2){
            float4 s4 = bufA[wv][0][k4];
            float4 s5 = bufA[wv][0][k4+1];
            float4 t4 = bufA[wv][1][k4];
            float4 t5 = bufA[wv][1][k4+1];
            int k = k4*4;
            float w;
            w = WfIn[(k+0)*64 + lane]; a0 += s4.x*w; e0 += t4.x*w;
            w = WfIn[(k+1)*64 + lane]; a1 += s4.y*w; e1 += t4.y*w;
            w = WfIn[(k+2)*64 + lane]; a2 += s4.z*w; e2 += t4.z*w;
            w = WfIn[(k+3)*64 + lane]; a3 += s4.w*w; e3 += t4.w*w;
            w = WfIn[(k+4)*64 + lane]; a0 += s5.x*w; e0 += t5.x*w;
            w = WfIn[(k+5)*64 + lane]; a1 += s5.y*w; e1 += t5.y*w;
            w = WfIn[(k+6)*64 + lane]; a2 += s5.z*w; e2 += t5.z*w;
            w = WfIn[(k+7)*64 + lane]; a3 += s5.w*w; e3 += t5.w*w;
        }
        ((float*)&bufB[wv][0][0])[lane] = fmaxf((a0 + a1) + (a2 + a3), 0.f);
        ((float*)&bufB[wv][1][0])[lane] = fmaxf((e0 + e1) + (e2 + e3), 0.f);

        // layer 2
        float c0_ = fbMid[lane], c1_ = 0.f, c2_ = 0.f, c3_ = 0.f;
        float g0_ = fbMid[lane], g1_ = 0.f, g2_ = 0.f, g3_ = 0.f;
#pragma unroll
        for (int k4 = 0; k4 < 16; k4 += 2){
            float4 s4 = bufB[wv][0][k4];
            float4 s5 = bufB[wv][0][k4+1];
            float4 t4 = bufB[wv][1][k4];
            float4 t5 = bufB[wv][1][k4+1];
            int k = k4*4;
            float w;
            w = WfMid[(k+0)*64 + lane]; c0_ += s4.x*w; g0_ += t4.x*w;
            w = WfMid[(k+1)*64 + lane]; c1_ += s4.y*w; g1_ += t4.y*w;
            w = WfMid[(k+2)*64 + lane]; c2_ += s4.z*w; g2_ += t4.z*w;
            w = WfMid[(k+3)*64 + lane]; c3_ += s4.w*w; g3_ += t4.w*w;
            w = WfMid[(k+4)*64 + lane]; c0_ += s5.x*w; g0_ += t5.x*w;
            w = WfMid[(k+5)*64 + lane]; c1_ += s5.y*w; g1_ += t5.y*w;
            w = WfMid[(k+6)*64 + lane]; c2_ += s5.z*w; g2_ += t5.z*w;
            w = WfMid[(k+7)*64 + lane]; c3_ += s5.w*w; g3_ += t5.w*w;
        }
        ((float*)&bufA[wv][0][0])[lane] = fmaxf((c0_ + c1_) + (c2_ + c3_), 0.f);
        ((float*)&bufA[wv][1][0])[lane] = fmaxf((g0_ + g1_) + (g2_ + g3_), 0.f);

        // layer 3 (64 -> 128, two output cols per lane)
        float p0a = fbOut[lane*2 + 0], p0b = 0.f;
        float p1a = fbOut[lane*2 + 1], p1b = 0.f;
        float q0a = fbOut[lane*2 + 0], q0b = 0.f;
        float q1a = fbOut[lane*2 + 1], q1b = 0.f;
#pragma unroll
        for (int k4 = 0; k4 < 16; k4 += 2){
            float4 s4 = bufA[wv][0][k4];
            float4 s5 = bufA[wv][0][k4+1];
            float4 t4 = bufA[wv][1][k4];
            float4 t5 = bufA[wv][1][k4+1];
            int k = k4*4;
            float w0, w1;
            w0 = WfOut[(k+0)*128 + lane*2+0]; w1 = WfOut[(k+0)*128 + lane*2+1];
            p0a += s4.x*w0; p1a += s4.x*w1; q0a += t4.x*w0; q1a += t4.x*w1;
            w0 = WfOut[(k+1)*128 + lane*2+0]; w1 = WfOut[(k+1)*128 + lane*2+1];
            p0b += s4.y*w0; p1b += s4.y*w1; q0b += t4.y*w0; q1b += t4.y*w1;
            w0 = WfOut[(k+2)*128 + lane*2+0]; w1 = WfOut[(k+2)*128 + lane*2+1];
            p0a += s4.z*w0; p1a += s4.z*w1; q0a += t4.z*w0; q1a += t4.z*w1;
            w0 = WfOut[(k+3)*128 + lane*2+0]; w1 = WfOut[(k+3)*128 + lane*2+1];
            p0b += s4.w*w0; p1b += s4.w*w1; q0b += t4.w*w0; q1b += t4.w*w1;
            w0 = WfOut[(k+4)*128 + lane*2+0]; w1 = WfOut[(k+4)*128 + lane*2+1];
            p0a += s5.x*w0; p1a += s5.x*w1; q0a += t5.x*w0; q1a += t5.x*w1;
            w0 = WfOut[(k+5)*128 + lane*2+0]; w1 = WfOut[(k+5)*128 + lane*2+1];
            p0b += s5.y*w0; p1b += s5.y*w1; q0b += t5.y*w0; q1b += t5.y*w1;
            w0 = WfOut[(k+6)*128 + lane*2+0]; w1 = WfOut[(k+6)*128 + lane*2+1];
            p0a += s5.z*w0; p1a += s5.z*w1; q0a += t5.z*w0; q1a += t5.z*w1;
            w0 = WfOut[(k+7)*128 + lane*2+0]; w1 = WfOut[(k+7)*128 + lane*2+1];
            p0b += s5.w*w0; p1b += s5.w*w1; q0b += t5.w*w0; q1b += t5.w*w1;
        }
        float f00 = tanh_fast(p0a + p0b);
        float f01 = tanh_fast(p1a + p1b);
        float f10 = tanh_fast(q0a + q0b);
        float f11 = tanh_fast(q1a + q1b);

        int cb0 = (bn0*NI + idx)*2;
        int cb1 = cb0 + NI*2;
        float dx00 = Cb[cb0]   + (Cc[cb0]   + Cd[cb0]*frac)*frac;
        float dx01 = Cb[cb0+1] + (Cc[cb0+1] + Cd[cb0+1]*frac)*frac;
        float dx10 = Cb[cb1]   + (Cc[cb1]   + Cd[cb1]*frac)*frac;
        float dx11 = Cb[cb1+1] + (Cc[cb1+1] + Cd[cb1+1]*frac)*frac;

        float kh0 = f00*dx00 + f01*dx01;
        float kh1 = f10*dx10 + f11*dx11;
        khAll[(size_t)stage*STG_STRIDE + base0]      = kh0;
        khAll[(size_t)stage*STG_STRIDE + base0 + 64] = kh1;
        if (s == 0)     { acch0 = kh0;        acch1 = kh1; }
        else if (s < 3) { acch0 += 2.f*kh0;   acch1 += 2.f*kh1; }
        else            { hv0 += (1.f/6.f)*(acch0 + kh0); hv1 += (1.f/6.f)*(acch1 + kh1); }
        khp0 = kh0; khp1 = kh1;
    }
}

// ---------- KXZ: fused x-compute (MFMA) + graph mix, grid 320 = (b,nt16) ----------
// Each block recomputes x for its whole batch (20x redundant, MFMA-cheap); wave wv
// writes xLT rows [wv*16, wv*16+16) and reads exactly those in phase 2 -> no barrier.
__global__ __launch_bounds__(256) void KXZ(
    const float* __restrict__ z, const float* __restrict__ kz,
    const unsigned short* __restrict__ WgInT, const float* __restrict__ gbIn,
    const unsigned short* __restrict__ Abf,
    unsigned short* __restrict__ xbf, unsigned short* __restrict__ xgbf,
    int stage, float acoef)
{
    __shared__ unsigned short xLT[64*328];   // [c][m], row stride 328 (656B = 41*16B aligned)
    int tid = threadIdx.x, lane = tid & 63, wv = tid >> 6;
    int quad = lane >> 4, l15 = lane & 15;
    int b = blockIdx.x / 20, nt = blockIdx.x % 20;
    int n0 = nt*16;
    int cc = wv*16 + l15;                    // this wave's column / xLT row

    bf16x8 wb0 = *(const bf16x8*)(WgInT + cc*64 + quad*8);
    bf16x8 wb1 = *(const bf16x8*)(WgInT + cc*64 + 32 + quad*8);
    float gb = gbIn[cc];
    bool writer = (nt == 0);

#pragma unroll 1
    for (int mt = 0; mt < 20; mt++){
        int m = mt*16 + l15;                 // A-operand row
        bf16x8 af0 = {0,0,0,0,0,0,0,0};
        bf16x8 af1 = {0,0,0,0,0,0,0,0};
        if (m < NN){
            const float* zp = z + ((size_t)b*NN + m)*64;
            float4 x0 = *(const float4*)(zp + quad*8);
            float4 x1 = *(const float4*)(zp + quad*8 + 4);
            float4 y0 = *(const float4*)(zp + 32 + quad*8);
            float4 y1 = *(const float4*)(zp + 32 + quad*8 + 4);
            if (stage > 0){
                const float* kp = kz + ((size_t)b*NN + m)*64;
                float4 k0 = *(const float4*)(kp + quad*8);
                float4 k1 = *(const float4*)(kp + quad*8 + 4);
                float4 k2 = *(const float4*)(kp + 32 + quad*8);
                float4 k3 = *(const float4*)(kp + 32 + quad*8 + 4);
                x0.x += acoef*k0.x; x0.y += acoef*k0.y; x0.z += acoef*k0.z; x0.w += acoef*k0.w;
                x1.x += acoef*k1.x; x1.y += acoef*k1.y; x1.z += acoef*k1.z; x1.w += acoef*k1.w;
                y0.x += acoef*k2.x; y0.y += acoef*k2.y; y0.z += acoef*k2.z; y0.w += acoef*k2.w;
                y1.x += acoef*k3.x; y1.y += acoef*k3.y; y1.z += acoef*k3.z; y1.w += acoef*k3.w;
            }
            unsigned short* p0 = (unsigned short*)&af0;
            unsigned short* p1 = (unsigned short*)&af1;
            p0[0]=f2bf(x0.x); p0[1]=f2bf(x0.y); p0[2]=f2bf(x0.z); p0[3]=f2bf(x0.w);
            p0[4]=f2bf(x1.x); p0[5]=f2bf(x1.y); p0[6]=f2bf(x1.z); p0[7]=f2bf(x1.w);
            p1[0]=f2bf(y0.x); p1[1]=f2bf(y0.y); p1[2]=f2bf(y0.z); p1[3]=f2bf(y0.w);
            p1[4]=f2bf(y1.x); p1[5]=f2bf(y1.y); p1[6]=f2bf(y1.z); p1[7]=f2bf(y1.w);
        }
        f32x4 acc = {0.f,0.f,0.f,0.f};
        acc = __builtin_amdgcn_mfma_f32_16x16x32_bf16(af0, wb0, acc, 0, 0, 0);
        acc = __builtin_amdgcn_mfma_f32_16x16x32_bf16(af1, wb1, acc, 0, 0, 0);
        // D rows m = mt*16 + quad*4 + r, col cc
        bf16x4 pk;
#pragma unroll
        for (int r = 0; r < 4; r++){
            int mm = mt*16 + quad*4 + r;
            unsigned short v = f2bf(fmaxf(acc[r] + gb, 0.f));
            ((unsigned short*)&pk)[r] = v;
            if (writer && mm < NN) xbf[((size_t)mm*16 + b)*64 + cc] = v;
        }
        *(bf16x4*)(xLT + cc*328 + mt*16 + quad*4) = pk;
    }

    // phase 2: xg for nodes n0..n0+15, cols cc (own-wave xLT rows only)
    f32x4 acc = {0.f,0.f,0.f,0.f};
#pragma unroll
    for (int mt2 = 0; mt2 < 10; mt2++){
        bf16x8 a  = *(const bf16x8*)(Abf + (size_t)(n0 + l15)*320 + mt2*32 + quad*8);
        bf16x8 bb = *(const bf16x8*)(xLT + cc*328 + mt2*32 + quad*8);
        acc = __builtin_amdgcn_mfma_f32_16x16x32_bf16(a, bb, acc, 0, 0, 0);
    }
#pragma unroll
    for (int r = 0; r < 4; r++){
        int n = n0 + quad*4 + r;
        xgbf[((size_t)n*16 + b)*64 + cc] = f2bf(acc[r]);
    }
}

// ---------- K2f: fused Y-compute + DMA-staged Wt GEMM + tanh*kh + RK4 z (R10, proven) ----------
__global__ __launch_bounds__(256, 3) void K2f(
    float* __restrict__ z, const float* __restrict__ khS,
    float* __restrict__ kz, float* __restrict__ accz,
    const unsigned short* __restrict__ xbf, const unsigned short* __restrict__ xgbf,
    const unsigned short* __restrict__ agcWt, const float* __restrict__ agcb,
    const unsigned short* __restrict__ Wt_sw, const float* __restrict__ gbOut,
    int stage)
{
    __shared__ unsigned short WtL[256*64];
    __shared__ unsigned short Ybf[64*68];
    __shared__ float dzl[4*16*5];
    int tid = threadIdx.x, lane = tid & 63, wv = tid >> 6;
    int quad = lane >> 4, l15 = lane & 15;
    int nt = blockIdx.x >> 4, cg = blockIdx.x & 15;
    int n0 = nt*4;
    int nw = n0 + wv;
    int n = nw < NN ? nw : NN-1;
    int C0 = cg*256;

#pragma unroll
    for (int it = 0; it < 8; it++){
        int seg = it*256 + wv*64 + lane;
        const unsigned short* src = Wt_sw + (size_t)C0*64 + (size_t)seg*8;
        __builtin_amdgcn_global_load_lds(
            (const __attribute__((address_space(1))) void*)src,
            (__attribute__((address_space(3))) void*)(WtL + (it*256 + wv*64)*8),
            16, 0, 0);
    }

    float4 khr[4];
#pragma unroll
    for (int c = 0; c < 4; c++)
        khr[c] = *(const float4*)(khS + ((size_t)l15*NN + n)*64 + c*16 + quad*4);

    {
        const size_t xrow = ((size_t)n*16 + l15)*64;
        bf16x8 a[4];
        a[0] = *(const bf16x8*)(xbf  + xrow + 0  + quad*8);
        a[1] = *(const bf16x8*)(xbf  + xrow + 32 + quad*8);
        a[2] = *(const bf16x8*)(xgbf + xrow + 0  + quad*8);
        a[3] = *(const bf16x8*)(xgbf + xrow + 32 + quad*8);
#pragma unroll
        for (int ot = 0; ot < 4; ot++){
            f32x4 acc = {0.f,0.f,0.f,0.f};
#pragma unroll
            for (int kt = 0; kt < 4; kt++){
                bf16x8 bbb = *(const bf16x8*)(agcWt + ((size_t)n*64 + ot*16 + l15)*128 + kt*32 + quad*8);
                acc = __builtin_amdgcn_mfma_f32_16x16x32_bf16(a[kt], bbb, acc, 0, 0, 0);
            }
            float gb = agcb[n*64 + ot*16 + l15];
#pragma unroll
            for (int r = 0; r < 4; r++)
                Ybf[(wv*16 + quad*4 + r)*68 + ot*16 + l15] = f2bf(fmaxf(acc[r] + gb, 0.f));
        }
    }

    __syncthreads();

    bf16x8 bb0 = *(const bf16x8*)(Ybf + (wv*16 + l15)*68 + 0  + quad*8);
    bf16x8 bb1 = *(const bf16x8*)(Ybf + (wv*16 + l15)*68 + 32 + quad*8);

    int sw = l15 & 7;
#pragma unroll
    for (int i4 = 0; i4 < 4; i4++){
        float pacc = 0.f;
#pragma unroll
        for (int c4 = 0; c4 < 4; c4++){
            int ct = i4*4 + c4;
            int row = ct*16 + l15;
            f32x4 acc = {0.f,0.f,0.f,0.f};
            bf16x8 a0 = *(const bf16x8*)(WtL + row*64 + (((quad)     ^ sw) << 3));
            acc = __builtin_amdgcn_mfma_f32_16x16x32_bf16(a0, bb0, acc, 0, 0, 0);
            bf16x8 a1 = *(const bf16x8*)(WtL + row*64 + (((4 + quad) ^ sw) << 3));
            acc = __builtin_amdgcn_mfma_f32_16x16x32_bf16(a1, bb1, acc, 0, 0, 0);
            float4 gb4 = *(const float4*)(gbOut + C0 + ct*16 + quad*4);
            float4 kh4 = khr[c4];
            pacc += tanh_fast(acc[0] + gb4.x) * kh4.x
                  + tanh_fast(acc[1] + gb4.y) * kh4.y
                  + tanh_fast(acc[2] + gb4.z) * kh4.z
                  + tanh_fast(acc[3] + gb4.w) * kh4.w;
        }
        pacc += __shfl_xor(pacc, 16, 64);
        pacc += __shfl_xor(pacc, 32, 64);
        if (quad == 0) dzl[(wv*16 + l15)*5 + i4] = pacc;
    }

    {
        int w = tid >> 6, bb_ = (tid >> 2) & 15, il = tid & 3;
        int nn = n0 + w;
        if (nn < NN){
            size_t addr = ((size_t)bb_*NN + nn)*64 + cg*4 + il;
            float v = dzl[(w*16 + bb_)*5 + il];
            kz[addr] = v;
            if (stage == 0)      accz[addr] = v;
            else if (stage < 3)  accz[addr] += 2.f*v;
            else                 z[addr] += (1.f/6.f)*(accz[addr] + v);
        }
    }
}

// ---------- output ----------
__global__ __launch_bounds__(256) void kOut(const float* __restrict__ z,
                                            const float* __restrict__ convW,
                                            const float* __restrict__ convB,
                                            float* __restrict__ out){
    int gid = blockIdx.x*256 + threadIdx.x;
    if (gid >= NB*NN) return;
    int b = gid / NN, n = gid % NN;
    float zr[64];
    const float4* zp = (const float4*)(z + (size_t)gid*64);
#pragma unroll
    for (int k4 = 0; k4 < 16; k4++){
        float4 v = zp[k4];
        zr[k4*4+0] = v.x; zr[k4*4+1] = v.y; zr[k4*4+2] = v.z; zr[k4*4+3] = v.w;
    }
#pragma unroll
    for (int o = 0; o < 12; o++){
        float acc = convB[o];
#pragma unroll
        for (int hh = 0; hh < 64; hh++) acc += zr[hh]*convW[o*64 + hh];
        out[(b*12 + o)*NN + n] = acc;
    }
}

extern "C" void kernel_launch(void* const* d_in, const int* in_sizes, int n_in,
                              void* d_out, int out_size, void* d_ws, size_t ws_size,
                              hipStream_t stream)
{
    const float* coeff_a = (const float*)d_in[0];
    const float* coeff_b = (const float*)d_in[1];
    const float* coeff_c = (const float*)d_in[2];
    const float* coeff_d = (const float*)d_in[3];
    const float* hW     = (const float*)d_in[5];
    const float* hb     = (const float*)d_in[6];
    const float* zW     = (const float*)d_in[7];
    const float* zb     = (const float*)d_in[8];
    const float* WfIn   = (const float*)d_in[9];
    const float* fbIn   = (const float*)d_in[10];
    const float* WfMid  = (const float*)d_in[11];
    const float* fbMid  = (const float*)d_in[12];
    const float* WfOut  = (const float*)d_in[13];
    const float* fbOut  = (const float*)d_in[14];
    const float* WgIn   = (const float*)d_in[15];
    const float* gbIn   = (const float*)d_in[16];
    const float* gE     = (const float*)d_in[17];
    const float* gWpool = (const float*)d_in[18];
    const float* gbpool = (const float*)d_in[19];
    const float* WgOut  = (const float*)d_in[20];
    const float* gbOut  = (const float*)d_in[21];
    const float* convW  = (const float*)d_in[22];
    const float* convB  = (const float*)d_in[23];

    float* ws = (float*)d_ws;
    unsigned short* Abf   = (unsigned short*)(ws + OFF_ABF);
    unsigned short* agcWt = (unsigned short*)(ws + OFF_AGCWT);
    float*          agcb  = ws + OFF_AGCB;
    unsigned short* Wt_sw = (unsigned short*)(ws + OFF_WT);
    float* h     = ws + OFF_H;
    float* z     = ws + OFF_Z;
    float* kz    = ws + OFF_KZ;
    float* accz  = ws + OFF_ACCZ;
    unsigned short* xbf   = (unsigned short*)(ws + OFF_XBF);
    unsigned short* xgbf  = (unsigned short*)(ws + OFF_XGBF);
    unsigned short* WgInT = (unsigned short*)(ws + OFF_WGINT);
    float* khAll = ws + OFF_KHALL;
    float* out = (float*)d_out;

    kA     <<<320, 64,  0, stream>>>(gE, Abf);
    kAgcWT <<<NN,  256, 0, stream>>>(gE, gWpool, agcWt);
    kAgcB  <<<77,  256, 0, stream>>>(gE, gbpool, agcb);
    kWt    <<<64,  256, 0, stream>>>(WgOut, Wt_sw);
    kWgInT <<<16,  256, 0, stream>>>(WgIn, WgInT);
    kInit  <<<1228,256, 0, stream>>>(coeff_a, hW, hb, zW, zb, h, z);

    KH<<<614, 256, 0, stream>>>(h, khAll, coeff_b, coeff_c, coeff_d,
                                WfIn, fbIn, WfMid, fbMid, WfOut, fbOut);

    const float acoef[4] = {0.f, 0.5f, 0.5f, 1.f};
    for (int step = 0; step < 11; step++){
        for (int s = 0; s < 4; s++){
            const float* khS = khAll + (size_t)(step*4 + s)*STG_STRIDE;
            KXZ<<<320, 256, 0, stream>>>(z, kz, WgInT, gbIn, Abf,
                                         xbf, xgbf, s, acoef[s]);
            K2f<<<1232, 256, 0, stream>>>(z, khS, kz, accz, xbf, xgbf,
                                          agcWt, agcb, Wt_sw, gbOut, s);
        }
    }
    kOut<<<20, 256, 0, stream>>>(z, convW, convB, out);
}

// Round 13
// 2029.970 us; speedup vs baseline: 1.5978x; 1.5978x over previous
//
#include <hip/hip_runtime.h>

#define NB 16
#define NN 307
#define NI 11

typedef __attribute__((ext_vector_type(8))) short bf16x8;
typedef __attribute__((ext_vector_type(4))) float f32x4;

// ws offsets in FLOAT units (ws ~256 MiB per harness fill size)
#define OFF_ABF    0u          // 320x320 bf16 = 51200 fl
#define OFF_AGCWT  51200u      // 307*64*128 bf16 = 1257472 fl
#define OFF_AGCB   1308672u    // 307*64 f32 -> pad 20480
#define OFF_WT     1329152u    // 4096*64 bf16 = 131072 fl (seg-swizzled)
#define OFF_H      1460224u    // 16*307*64 = 314368 fl
#define OFF_Z      1774592u
#define OFF_KZ     2088960u
#define OFF_ACCZ   2403328u
#define OFF_XBF    2717696u    // 320*16*64 bf16 = 163840 fl
#define OFF_XGBF   2881536u
#define OFF_XT     3045376u    // 16*64*320 bf16 = 163840 fl
#define OFF_KHALL  3209216u    // 44 * 314368 f32 ; end ~68 MB

#define STG_STRIDE 314368u

__device__ __forceinline__ float tanh_fast(float x){
    float e = __expf(2.0f * x);
    return 1.0f - 2.0f * __builtin_amdgcn_rcpf(e + 1.0f);
}
__device__ __forceinline__ unsigned short f2bf(float f){
    unsigned u = __builtin_bit_cast(unsigned, f);
    unsigned r = u + 0x7FFFu + ((u >> 16) & 1u);
    return (unsigned short)(r >> 16);
}

// ---------- precompute ----------

__global__ void kA(const float* __restrict__ gE, unsigned short* __restrict__ Abf){
    int n = blockIdx.x;            // grid 320, 64 threads
    int lane = threadIdx.x;
    if (n >= NN){
#pragma unroll
        for (int ii = 0; ii < 5; ii++) Abf[n*320 + lane + 64*ii] = 0;
        return;
    }
    float en[8];
#pragma unroll
    for (int d = 0; d < 8; d++) en[d] = gE[n*8 + d];
    float vals[5];
    float mx = -1e30f;
#pragma unroll
    for (int ii = 0; ii < 5; ii++){
        int m = lane + 64*ii;
        float v = -1e30f;
        if (m < NN){
            float a = 0.f;
#pragma unroll
            for (int d = 0; d < 8; d++) a += en[d] * gE[m*8 + d];
            v = fmaxf(a, 0.f);
        }
        vals[ii] = v;
        mx = fmaxf(mx, v);
    }
#pragma unroll
    for (int off = 32; off >= 1; off >>= 1) mx = fmaxf(mx, __shfl_xor(mx, off, 64));
    float s = 0.f;
#pragma unroll
    for (int ii = 0; ii < 5; ii++){
        int m = lane + 64*ii;
        if (m < NN){ vals[ii] = __expf(vals[ii] - mx); s += vals[ii]; }
    }
#pragma unroll
    for (int off = 32; off >= 1; off >>= 1) s += __shfl_xor(s, off, 64);
    float inv = 1.f / s;
#pragma unroll
    for (int ii = 0; ii < 5; ii++){
        int m = lane + 64*ii;
        unsigned short v = 0;
        if (m < NN) v = f2bf(vals[ii] * inv);
        Abf[n*320 + m] = v;
    }
}

__global__ __launch_bounds__(256) void kAgcWT(const float* __restrict__ gE,
                                              const float* __restrict__ gWpool,
                                              unsigned short* __restrict__ agcWt){
    __shared__ float t[128*65];
    int tid = threadIdx.x;
    int n = blockIdx.x;            // grid 307
    float ge[8];
#pragma unroll
    for (int d = 0; d < 8; d++) ge[d] = gE[n*8 + d];
    for (int it = 0; it < 32; it++){
        int e = it*256 + tid;
        int o = e & 63, i = (e >> 6) & 63, kk = e >> 12;
        float acc = 0.f;
#pragma unroll
        for (int d = 0; d < 8; d++) acc += ge[d] * gWpool[((size_t)(d*2 + kk)*64 + i)*64 + o];
        t[(kk*64 + i)*65 + o] = acc;
    }
    __syncthreads();
    for (int it = 0; it < 32; it++){
        int e = it*256 + tid;
        int k = e & 127, o = e >> 7;
        agcWt[((size_t)n*64 + o)*128 + k] = f2bf(t[k*65 + o]);
    }
}

__global__ void kAgcB(const float* __restrict__ gE, const float* __restrict__ gbpool,
                      float* __restrict__ agcb){
    int gid = blockIdx.x*256 + threadIdx.x;
    if (gid >= NN*64) return;
    int o = gid & 63;
    int n = gid >> 6;
    float acc = 0.f;
#pragma unroll
    for (int d = 0; d < 8; d++) acc += gE[n*8 + d] * gbpool[d*64 + o];
    agcb[gid] = acc;
}

// Wt_sw[col][seg'] bf16 : transpose of WgOut with 16B-seg swizzle seg' = seg ^ (col&7)
__global__ __launch_bounds__(256) void kWt(const float* __restrict__ WgOut,
                                           unsigned short* __restrict__ Wt_sw){
    __shared__ float t[64*65];
    int tid = threadIdx.x;
    int c0 = blockIdx.x*64;        // grid 64
    for (int it = 0; it < 16; it++){
        int e = it*256 + tid;
        int k = e >> 6, c = e & 63;
        t[k*65 + c] = WgOut[(size_t)k*4096 + c0 + c];
    }
    __syncthreads();
    for (int it = 0; it < 16; it++){
        int e = it*256 + tid;
        int c = e >> 6, k = e & 63;
        int ks = ((((k >> 3) ^ (c & 7)) << 3) | (k & 7));
        Wt_sw[(size_t)(c0 + c)*64 + ks] = f2bf(t[k*65 + c]);
    }
}

__global__ void kZeroTail(unsigned short* __restrict__ xT){
    int gid = blockIdx.x*256 + threadIdx.x;   // 16*64*16 = 16384
    int mo = gid & 15, c = (gid >> 4) & 63, b = gid >> 10;
    xT[((size_t)b*64 + c)*320 + 304 + mo] = 0;
}

__global__ void kInit(const float* __restrict__ ca,
                      const float* __restrict__ hW, const float* __restrict__ hb,
                      const float* __restrict__ zW, const float* __restrict__ zb,
                      float* __restrict__ h, float* __restrict__ z){
    int gid = blockIdx.x*256 + threadIdx.x;   // exactly 314368
    int t = gid & 63;
    int bn = gid >> 6;
    float x0 = ca[bn*NI*2 + 0];
    float x1 = ca[bn*NI*2 + 1];
    h[gid] = x0*hW[t] + x1*hW[64 + t] + hb[t];
    z[gid] = x0*zW[t] + x1*zW[64 + t] + zb[t];
}

// ---------- KH: full h-ODE in one launch; weights staged ONCE into LDS ----------
// grid 1228 (1 row/wave, max TLP — R11 showed 2-row halves hiding); fp32 math,
// op order bitwise-identical to R10's proven KH. Weight set (64 KB) > L1 (32 KB)
// caused L1 thrash at 342 us; LDS staging removes it. WfOut de-interleaved into
// even/odd arrays so lane*2 striding becomes conflict-free lane-consecutive reads.
__global__ __launch_bounds__(256) void KH(
    const float* __restrict__ h0, float* __restrict__ khAll,
    const float* __restrict__ Cb, const float* __restrict__ Cc, const float* __restrict__ Cd,
    const float* __restrict__ WfIn, const float* __restrict__ fbIn,
    const float* __restrict__ WfMid, const float* __restrict__ fbMid,
    const float* __restrict__ WfOut, const float* __restrict__ fbOut)
{
    __shared__ float WfInL[4096];
    __shared__ float WfMidL[4096];
    __shared__ float WfOut0L[4096];   // WfOut[k][2j]
    __shared__ float WfOut1L[4096];   // WfOut[k][2j+1]
    __shared__ float4 bufA[4][16];
    __shared__ float4 bufB[4][16];
    int tid = threadIdx.x;
    int wv = tid >> 6;
    int lane = tid & 63;
    int bn = blockIdx.x*4 + wv;            // (b*307+n) in [0,4912)
    int base = bn*64 + lane;

    // one-time weight stage (then 44 stages of pure LDS reads)
    for (int e = tid; e < 4096; e += 256){
        WfInL[e]  = WfIn[e];
        WfMidL[e] = WfMid[e];
    }
    for (int e = tid; e < 8192; e += 256){
        int k = e >> 7, c = e & 127;
        float v = WfOut[e];
        if (c & 1) WfOut1L[k*64 + (c >> 1)] = v;
        else       WfOut0L[k*64 + (c >> 1)] = v;
    }
    __syncthreads();

    float hv = h0[base];
    float acch = 0.f, khprev = 0.f;

#pragma unroll 1
    for (int stage = 0; stage < 44; stage++){
        int step = stage >> 2, s = stage & 3;
        float acoef = (s == 0) ? 0.f : (s == 3 ? 1.f : 0.5f);
        int idx; float frac;
        if (s == 0)        { idx = step;     frac = 0.f;  }
        else if (s < 3)    { idx = step;     frac = 0.5f; }
        else if (step < 10){ idx = step + 1; frac = 0.f;  }
        else               { idx = 10;       frac = 1.f;  }

        float sih = hv + acoef * khprev;
        ((float*)&bufA[wv][0])[lane] = sih;

        float a0 = fbIn[lane], a1 = 0.f, a2 = 0.f, a3 = 0.f;
#pragma unroll
        for (int k4 = 0; k4 < 16; k4 += 2){
            float4 s4 = bufA[wv][k4];
            float4 s5 = bufA[wv][k4+1];
            int k = k4*4;
            a0 += s4.x*WfInL[(k+0)*64 + lane];
            a1 += s4.y*WfInL[(k+1)*64 + lane];
            a2 += s4.z*WfInL[(k+2)*64 + lane];
            a3 += s4.w*WfInL[(k+3)*64 + lane];
            a0 += s5.x*WfInL[(k+4)*64 + lane];
            a1 += s5.y*WfInL[(k+5)*64 + lane];
            a2 += s5.z*WfInL[(k+6)*64 + lane];
            a3 += s5.w*WfInL[(k+7)*64 + lane];
        }
        float u = fmaxf((a0 + a1) + (a2 + a3), 0.f);
        ((float*)&bufB[wv][0])[lane] = u;

        float c0_ = fbMid[lane], c1_ = 0.f, c2_ = 0.f, c3_ = 0.f;
#pragma unroll
        for (int k4 = 0; k4 < 16; k4 += 2){
            float4 s4 = bufB[wv][k4];
            float4 s5 = bufB[wv][k4+1];
            int k = k4*4;
            c0_ += s4.x*WfMidL[(k+0)*64 + lane];
            c1_ += s4.y*WfMidL[(k+1)*64 + lane];
            c2_ += s4.z*WfMidL[(k+2)*64 + lane];
            c3_ += s4.w*WfMidL[(k+3)*64 + lane];
            c0_ += s5.x*WfMidL[(k+4)*64 + lane];
            c1_ += s5.y*WfMidL[(k+5)*64 + lane];
            c2_ += s5.z*WfMidL[(k+6)*64 + lane];
            c3_ += s5.w*WfMidL[(k+7)*64 + lane];
        }
        float u2v = fmaxf((c0_ + c1_) + (c2_ + c3_), 0.f);
        ((float*)&bufA[wv][0])[lane] = u2v;

        float f0a = fbOut[lane*2 + 0], f0b = 0.f;
        float f1a = fbOut[lane*2 + 1], f1b = 0.f;
#pragma unroll
        for (int k4 = 0; k4 < 16; k4 += 2){
            float4 s4 = bufA[wv][k4];
            float4 s5 = bufA[wv][k4+1];
            int k = k4*4;
            f0a += s4.x*WfOut0L[(k+0)*64 + lane]; f1a += s4.x*WfOut1L[(k+0)*64 + lane];
            f0b += s4.y*WfOut0L[(k+1)*64 + lane]; f1b += s4.y*WfOut1L[(k+1)*64 + lane];
            f0a += s4.z*WfOut0L[(k+2)*64 + lane]; f1a += s4.z*WfOut1L[(k+2)*64 + lane];
            f0b += s4.w*WfOut0L[(k+3)*64 + lane]; f1b += s4.w*WfOut1L[(k+3)*64 + lane];
            f0a += s5.x*WfOut0L[(k+4)*64 + lane]; f1a += s5.x*WfOut1L[(k+4)*64 + lane];
            f0b += s5.y*WfOut0L[(k+5)*64 + lane]; f1b += s5.y*WfOut1L[(k+5)*64 + lane];
            f0a += s5.z*WfOut0L[(k+6)*64 + lane]; f1a += s5.z*WfOut1L[(k+6)*64 + lane];
            f0b += s5.w*WfOut0L[(k+7)*64 + lane]; f1b += s5.w*WfOut1L[(k+7)*64 + lane];
        }
        float f0 = tanh_fast(f0a + f0b);
        float f1 = tanh_fast(f1a + f1b);

        int cb = (bn*NI + idx)*2;
        float b0 = Cb[cb], b1 = Cb[cb+1];
        float c0 = Cc[cb], c1 = Cc[cb+1];
        float d0 = Cd[cb], d1 = Cd[cb+1];
        float dx0 = b0 + (c0 + d0*frac)*frac;
        float dx1 = b1 + (c1 + d1*frac)*frac;

        float khv = f0*dx0 + f1*dx1;
        khAll[(size_t)stage*STG_STRIDE + base] = khv;
        if (s == 0)      acch = khv;
        else if (s < 3)  acch += 2.f*khv;
        else             hv = hv + (1.f/6.f)*(acch + khv);
        khprev = khv;
    }
}

// ---------- Kz1: x = relu((z + acoef*kz) @ WgIn + gbIn) -> xbf (node-major) + xT ----------
__global__ __launch_bounds__(256) void Kz1(
    const float* __restrict__ z, const float* __restrict__ kz,
    unsigned short* __restrict__ xbf, unsigned short* __restrict__ xT,
    const float* __restrict__ WgIn, const float* __restrict__ gbIn,
    int stage, float acoef)
{
    __shared__ float4 bufZ[4][16];
    int tid = threadIdx.x;
    int wv = tid >> 6;
    int lane = tid & 63;
    int bn = blockIdx.x*4 + wv;
    int base = bn*64 + lane;
    int b = (int)((unsigned)bn / 307u);
    int n = bn - b*307;

    float siz = z[base];
    if (stage > 0) siz += acoef * kz[base];
    ((float*)&bufZ[wv][0])[lane] = siz;

    float xa = gbIn[lane], xb = 0.f;
#pragma unroll
    for (int k4 = 0; k4 < 16; k4 += 2){
        float4 z4 = bufZ[wv][k4];
        float4 z5 = bufZ[wv][k4+1];
        int k = k4*4;
        xa += z4.x*WgIn[(k+0)*64 + lane];
        xb += z4.y*WgIn[(k+1)*64 + lane];
        xa += z4.z*WgIn[(k+2)*64 + lane];
        xb += z4.w*WgIn[(k+3)*64 + lane];
        xa += z5.x*WgIn[(k+4)*64 + lane];
        xb += z5.y*WgIn[(k+5)*64 + lane];
        xa += z5.z*WgIn[(k+6)*64 + lane];
        xb += z5.w*WgIn[(k+7)*64 + lane];
    }
    unsigned short xbfv = f2bf(fmaxf(xa + xb, 0.f));
    xbf[((size_t)n*16 + b)*64 + lane] = xbfv;
    xT[((size_t)b*64 + lane)*320 + n] = xbfv;
}

// ---------- KXG: xg = A @ x per batch, pure-MFMA, no LDS. grid 320 ----------
__global__ __launch_bounds__(256) void KXG(
    const unsigned short* __restrict__ xT, const unsigned short* __restrict__ Abf,
    unsigned short* __restrict__ xgbf)
{
    int tid = threadIdx.x, lane = tid & 63, wv = tid >> 6;
    int quad = lane >> 4, l15 = lane & 15;
    int b = blockIdx.x / 20, nt = blockIdx.x % 20;
    int n0 = nt*16;

    f32x4 acc = {0.f,0.f,0.f,0.f};
#pragma unroll
    for (int mt = 0; mt < 10; mt++){
        bf16x8 a  = *(const bf16x8*)(Abf + (size_t)(n0 + l15)*320 + mt*32 + quad*8);
        bf16x8 bb = *(const bf16x8*)(xT + ((size_t)b*64 + wv*16 + l15)*320 + mt*32 + quad*8);
        acc = __builtin_amdgcn_mfma_f32_16x16x32_bf16(a, bb, acc, 0, 0, 0);
    }
#pragma unroll
    for (int r = 0; r < 4; r++){
        int n = n0 + quad*4 + r;
        xgbf[((size_t)n*16 + b)*64 + wv*16 + l15] = f2bf(acc[r]);
    }
}

// ---------- K2f: fused Y-compute + DMA-staged Wt GEMM + tanh*kh + RK4 z ----------
__global__ __launch_bounds__(256, 3) void K2f(
    float* __restrict__ z, const float* __restrict__ khS,
    float* __restrict__ kz, float* __restrict__ accz,
    const unsigned short* __restrict__ xbf, const unsigned short* __restrict__ xgbf,
    const unsigned short* __restrict__ agcWt, const float* __restrict__ agcb,
    const unsigned short* __restrict__ Wt_sw, const float* __restrict__ gbOut,
    int stage)
{
    __shared__ unsigned short WtL[256*64];
    __shared__ unsigned short Ybf[64*68];
    __shared__ float dzl[4*16*5];
    int tid = threadIdx.x, lane = tid & 63, wv = tid >> 6;
    int quad = lane >> 4, l15 = lane & 15;
    int nt = blockIdx.x >> 4, cg = blockIdx.x & 15;
    int n0 = nt*4;
    int nw = n0 + wv;
    int n = nw < NN ? nw : NN-1;
    int C0 = cg*256;

#pragma unroll
    for (int it = 0; it < 8; it++){
        int seg = it*256 + wv*64 + lane;
        const unsigned short* src = Wt_sw + (size_t)C0*64 + (size_t)seg*8;
        __builtin_amdgcn_global_load_lds(
            (const __attribute__((address_space(1))) void*)src,
            (__attribute__((address_space(3))) void*)(WtL + (it*256 + wv*64)*8),
            16, 0, 0);
    }

    float4 khr[4];
#pragma unroll
    for (int c = 0; c < 4; c++)
        khr[c] = *(const float4*)(khS + ((size_t)l15*NN + n)*64 + c*16 + quad*4);

    {
        const size_t xrow = ((size_t)n*16 + l15)*64;
        bf16x8 a[4];
        a[0] = *(const bf16x8*)(xbf  + xrow + 0  + quad*8);
        a[1] = *(const bf16x8*)(xbf  + xrow + 32 + quad*8);
        a[2] = *(const bf16x8*)(xgbf + xrow + 0  + quad*8);
        a[3] = *(const bf16x8*)(xgbf + xrow + 32 + quad*8);
#pragma unroll
        for (int ot = 0; ot < 4; ot++){
            f32x4 acc = {0.f,0.f,0.f,0.f};
#pragma unroll
            for (int kt = 0; kt < 4; kt++){
                bf16x8 bbb = *(const bf16x8*)(agcWt + ((size_t)n*64 + ot*16 + l15)*128 + kt*32 + quad*8);
                acc = __builtin_amdgcn_mfma_f32_16x16x32_bf16(a[kt], bbb, acc, 0, 0, 0);
            }
            float gb = agcb[n*64 + ot*16 + l15];
#pragma unroll
            for (int r = 0; r < 4; r++)
                Ybf[(wv*16 + quad*4 + r)*68 + ot*16 + l15] = f2bf(fmaxf(acc[r] + gb, 0.f));
        }
    }

    __syncthreads();

    bf16x8 bb0 = *(const bf16x8*)(Ybf + (wv*16 + l15)*68 + 0  + quad*8);
    bf16x8 bb1 = *(const bf16x8*)(Ybf + (wv*16 + l15)*68 + 32 + quad*8);

    int sw = l15 & 7;
#pragma unroll
    for (int i4 = 0; i4 < 4; i4++){
        float pacc = 0.f;
#pragma unroll
        for (int c4 = 0; c4 < 4; c4++){
            int ct = i4*4 + c4;
            int row = ct*16 + l15;
            f32x4 acc = {0.f,0.f,0.f,0.f};
            bf16x8 a0 = *(const bf16x8*)(WtL + row*64 + (((quad)     ^ sw) << 3));
            acc = __builtin_amdgcn_mfma_f32_16x16x32_bf16(a0, bb0, acc, 0, 0, 0);
            bf16x8 a1 = *(const bf16x8*)(WtL + row*64 + (((4 + quad) ^ sw) << 3));
            acc = __builtin_amdgcn_mfma_f32_16x16x32_bf16(a1, bb1, acc, 0, 0, 0);
            float4 gb4 = *(const float4*)(gbOut + C0 + ct*16 + quad*4);
            float4 kh4 = khr[c4];
            pacc += tanh_fast(acc[0] + gb4.x) * kh4.x
                  + tanh_fast(acc[1] + gb4.y) * kh4.y
                  + tanh_fast(acc[2] + gb4.z) * kh4.z
                  + tanh_fast(acc[3] + gb4.w) * kh4.w;
        }
        pacc += __shfl_xor(pacc, 16, 64);
        pacc += __shfl_xor(pacc, 32, 64);
        if (quad == 0) dzl[(wv*16 + l15)*5 + i4] = pacc;
    }

    {
        int w = tid >> 6, bb_ = (tid >> 2) & 15, il = tid & 3;
        int nn = n0 + w;
        if (nn < NN){
            size_t addr = ((size_t)bb_*NN + nn)*64 + cg*4 + il;
            float v = dzl[(w*16 + bb_)*5 + il];
            kz[addr] = v;
            if (stage == 0)      accz[addr] = v;
            else if (stage < 3)  accz[addr] += 2.f*v;
            else                 z[addr] += (1.f/6.f)*(accz[addr] + v);
        }
    }
}

// ---------- output ----------
__global__ __launch_bounds__(256) void kOut(const float* __restrict__ z,
                                            const float* __restrict__ convW,
                                            const float* __restrict__ convB,
                                            float* __restrict__ out){
    int gid = blockIdx.x*256 + threadIdx.x;
    if (gid >= NB*NN) return;
    int b = gid / NN, n = gid % NN;
    float zr[64];
    const float4* zp = (const float4*)(z + (size_t)gid*64);
#pragma unroll
    for (int k4 = 0; k4 < 16; k4++){
        float4 v = zp[k4];
        zr[k4*4+0] = v.x; zr[k4*4+1] = v.y; zr[k4*4+2] = v.z; zr[k4*4+3] = v.w;
    }
#pragma unroll
    for (int o = 0; o < 12; o++){
        float acc = convB[o];
#pragma unroll
        for (int hh = 0; hh < 64; hh++) acc += zr[hh]*convW[o*64 + hh];
        out[(b*12 + o)*NN + n] = acc;
    }
}

extern "C" void kernel_launch(void* const* d_in, const int* in_sizes, int n_in,
                              void* d_out, int out_size, void* d_ws, size_t ws_size,
                              hipStream_t stream)
{
    const float* coeff_a = (const float*)d_in[0];
    const float* coeff_b = (const float*)d_in[1];
    const float* coeff_c = (const float*)d_in[2];
    const float* coeff_d = (const float*)d_in[3];
    const float* hW     = (const float*)d_in[5];
    const float* hb     = (const float*)d_in[6];
    const float* zW     = (const float*)d_in[7];
    const float* zb     = (const float*)d_in[8];
    const float* WfIn   = (const float*)d_in[9];
    const float* fbIn   = (const float*)d_in[10];
    const float* WfMid  = (const float*)d_in[11];
    const float* fbMid  = (const float*)d_in[12];
    const float* WfOut  = (const float*)d_in[13];
    const float* fbOut  = (const float*)d_in[14];
    const float* WgIn   = (const float*)d_in[15];
    const float* gbIn   = (const float*)d_in[16];
    const float* gE     = (const float*)d_in[17];
    const float* gWpool = (const float*)d_in[18];
    const float* gbpool = (const float*)d_in[19];
    const float* WgOut  = (const float*)d_in[20];
    const float* gbOut  = (const float*)d_in[21];
    const float* convW  = (const float*)d_in[22];
    const float* convB  = (const float*)d_in[23];

    float* ws = (float*)d_ws;
    unsigned short* Abf   = (unsigned short*)(ws + OFF_ABF);
    unsigned short* agcWt = (unsigned short*)(ws + OFF_AGCWT);
    float*          agcb  = ws + OFF_AGCB;
    unsigned short* Wt_sw = (unsigned short*)(ws + OFF_WT);
    float* h     = ws + OFF_H;
    float* z     = ws + OFF_Z;
    float* kz    = ws + OFF_KZ;
    float* accz  = ws + OFF_ACCZ;
    unsigned short* xbf  = (unsigned short*)(ws + OFF_XBF);
    unsigned short* xgbf = (unsigned short*)(ws + OFF_XGBF);
    unsigned short* xT   = (unsigned short*)(ws + OFF_XT);
    float* khAll = ws + OFF_KHALL;
    float* out = (float*)d_out;

    kA        <<<320, 64,  0, stream>>>(gE, Abf);
    kAgcWT    <<<NN,  256, 0, stream>>>(gE, gWpool, agcWt);
    kAgcB     <<<77,  256, 0, stream>>>(gE, gbpool, agcb);
    kWt       <<<64,  256, 0, stream>>>(WgOut, Wt_sw);
    kZeroTail <<<64,  256, 0, stream>>>(xT);
    kInit     <<<1228,256, 0, stream>>>(coeff_a, hW, hb, zW, zb, h, z);

    // one launch: full h-ODE, all 44 stage kh slabs (LDS-staged weights)
    KH<<<1228, 256, 0, stream>>>(h, khAll, coeff_b, coeff_c, coeff_d,
                                 WfIn, fbIn, WfMid, fbMid, WfOut, fbOut);

    const float acoef[4] = {0.f, 0.5f, 0.5f, 1.f};
    for (int step = 0; step < 11; step++){
        for (int s = 0; s < 4; s++){
            const float* khS = khAll + (size_t)(step*4 + s)*STG_STRIDE;
            Kz1<<<1228, 256, 0, stream>>>(z, kz, xbf, xT, WgIn, gbIn, s, acoef[s]);
            KXG<<<320, 256, 0, stream>>>(xT, Abf, xgbf);
            K2f<<<1232, 256, 0, stream>>>(z, khS, kz, accz, xbf, xgbf,
                                          agcWt, agcb, Wt_sw, gbOut, s);
        }
    }
    kOut<<<20, 256, 0, stream>>>(z, convW, convB, out);
}

// Round 14
// 1996.967 us; speedup vs baseline: 1.6242x; 1.0165x over previous
//
#include <hip/hip_runtime.h>

#define NB 16
#define NN 307
#define NI 11

typedef __attribute__((ext_vector_type(8))) short bf16x8;
typedef __attribute__((ext_vector_type(4))) float f32x4;

// ws offsets in FLOAT units (ws ~256 MiB per harness fill size)
#define OFF_ABF    0u          // 320x320 bf16 = 51200 fl
#define OFF_AGCWT  51200u      // 307*64*128 bf16 = 1257472 fl
#define OFF_AGCB   1308672u    // 307*64 f32 -> pad 20480
#define OFF_WT     1329152u    // 4096*64 bf16 = 131072 fl (seg-swizzled)
#define OFF_H      1460224u    // 16*307*64 = 314368 fl
#define OFF_Z      1774592u
#define OFF_KZ     2088960u
#define OFF_ACCZ   2403328u
#define OFF_XBF    2717696u    // 320*16*64 bf16 = 163840 fl
#define OFF_XGBF   2881536u
#define OFF_XT     3045376u    // 16*64*320 bf16 = 163840 fl
#define OFF_KHALL  3209216u    // 44 * 314368 f32 ; end ~68 MB

#define STG_STRIDE 314368u

__device__ __forceinline__ float tanh_fast(float x){
    float e = __expf(2.0f * x);
    return 1.0f - 2.0f * __builtin_amdgcn_rcpf(e + 1.0f);
}
__device__ __forceinline__ unsigned short f2bf(float f){
    unsigned u = __builtin_bit_cast(unsigned, f);
    unsigned r = u + 0x7FFFu + ((u >> 16) & 1u);
    return (unsigned short)(r >> 16);
}

// ---------- precompute ----------

__global__ void kA(const float* __restrict__ gE, unsigned short* __restrict__ Abf){
    int n = blockIdx.x;            // grid 320, 64 threads
    int lane = threadIdx.x;
    if (n >= NN){
#pragma unroll
        for (int ii = 0; ii < 5; ii++) Abf[n*320 + lane + 64*ii] = 0;
        return;
    }
    float en[8];
#pragma unroll
    for (int d = 0; d < 8; d++) en[d] = gE[n*8 + d];
    float vals[5];
    float mx = -1e30f;
#pragma unroll
    for (int ii = 0; ii < 5; ii++){
        int m = lane + 64*ii;
        float v = -1e30f;
        if (m < NN){
            float a = 0.f;
#pragma unroll
            for (int d = 0; d < 8; d++) a += en[d] * gE[m*8 + d];
            v = fmaxf(a, 0.f);
        }
        vals[ii] = v;
        mx = fmaxf(mx, v);
    }
#pragma unroll
    for (int off = 32; off >= 1; off >>= 1) mx = fmaxf(mx, __shfl_xor(mx, off, 64));
    float s = 0.f;
#pragma unroll
    for (int ii = 0; ii < 5; ii++){
        int m = lane + 64*ii;
        if (m < NN){ vals[ii] = __expf(vals[ii] - mx); s += vals[ii]; }
    }
#pragma unroll
    for (int off = 32; off >= 1; off >>= 1) s += __shfl_xor(s, off, 64);
    float inv = 1.f / s;
#pragma unroll
    for (int ii = 0; ii < 5; ii++){
        int m = lane + 64*ii;
        unsigned short v = 0;
        if (m < NN) v = f2bf(vals[ii] * inv);
        Abf[n*320 + m] = v;
    }
}

__global__ __launch_bounds__(256) void kAgcWT(const float* __restrict__ gE,
                                              const float* __restrict__ gWpool,
                                              unsigned short* __restrict__ agcWt){
    __shared__ float t[128*65];
    int tid = threadIdx.x;
    int n = blockIdx.x;            // grid 307
    float ge[8];
#pragma unroll
    for (int d = 0; d < 8; d++) ge[d] = gE[n*8 + d];
    for (int it = 0; it < 32; it++){
        int e = it*256 + tid;
        int o = e & 63, i = (e >> 6) & 63, kk = e >> 12;
        float acc = 0.f;
#pragma unroll
        for (int d = 0; d < 8; d++) acc += ge[d] * gWpool[((size_t)(d*2 + kk)*64 + i)*64 + o];
        t[(kk*64 + i)*65 + o] = acc;
    }
    __syncthreads();
    for (int it = 0; it < 32; it++){
        int e = it*256 + tid;
        int k = e & 127, o = e >> 7;
        agcWt[((size_t)n*64 + o)*128 + k] = f2bf(t[k*65 + o]);
    }
}

__global__ void kAgcB(const float* __restrict__ gE, const float* __restrict__ gbpool,
                      float* __restrict__ agcb){
    int gid = blockIdx.x*256 + threadIdx.x;
    if (gid >= NN*64) return;
    int o = gid & 63;
    int n = gid >> 6;
    float acc = 0.f;
#pragma unroll
    for (int d = 0; d < 8; d++) acc += gE[n*8 + d] * gbpool[d*64 + o];
    agcb[gid] = acc;
}

// Wt_sw[col][seg'] bf16 : transpose of WgOut with 16B-seg swizzle seg' = seg ^ (col&7)
__global__ __launch_bounds__(256) void kWt(const float* __restrict__ WgOut,
                                           unsigned short* __restrict__ Wt_sw){
    __shared__ float t[64*65];
    int tid = threadIdx.x;
    int c0 = blockIdx.x*64;        // grid 64
    for (int it = 0; it < 16; it++){
        int e = it*256 + tid;
        int k = e >> 6, c = e & 63;
        t[k*65 + c] = WgOut[(size_t)k*4096 + c0 + c];
    }
    __syncthreads();
    for (int it = 0; it < 16; it++){
        int e = it*256 + tid;
        int c = e >> 6, k = e & 63;
        int ks = ((((k >> 3) ^ (c & 7)) << 3) | (k & 7));
        Wt_sw[(size_t)(c0 + c)*64 + ks] = f2bf(t[k*65 + c]);
    }
}

__global__ void kZeroTail(unsigned short* __restrict__ xT){
    int gid = blockIdx.x*256 + threadIdx.x;   // 16*64*16 = 16384
    int mo = gid & 15, c = (gid >> 4) & 63, b = gid >> 10;
    xT[((size_t)b*64 + c)*320 + 304 + mo] = 0;
}

__global__ void kInit(const float* __restrict__ ca,
                      const float* __restrict__ hW, const float* __restrict__ hb,
                      const float* __restrict__ zW, const float* __restrict__ zb,
                      float* __restrict__ h, float* __restrict__ z){
    int gid = blockIdx.x*256 + threadIdx.x;   // exactly 314368
    int t = gid & 63;
    int bn = gid >> 6;
    float x0 = ca[bn*NI*2 + 0];
    float x1 = ca[bn*NI*2 + 1];
    h[gid] = x0*hW[t] + x1*hW[64 + t] + hb[t];
    z[gid] = x0*zW[t] + x1*zW[64 + t] + zb[t];
}

// ---------- KH: full h-ODE in one launch; transposed+swizzled LDS weights ----------
// grid 1228 (1 row/wave). Weights stored row-per-lane [col][k] with 16B-seg XOR
// swizzle (seg' = seg ^ (col&15)) -> 16 conflict-free ds_read_b128 per layer
// instead of 64 ds_read_b32 (R12 was LDS-issue bound at 283 us, VALUBusy 43%).
// FMA products and order identical to R12 -> bitwise-same h-path.
__global__ __launch_bounds__(256) void KH(
    const float* __restrict__ h0, float* __restrict__ khAll,
    const float* __restrict__ Cb, const float* __restrict__ Cc, const float* __restrict__ Cd,
    const float* __restrict__ WfIn, const float* __restrict__ fbIn,
    const float* __restrict__ WfMid, const float* __restrict__ fbMid,
    const float* __restrict__ WfOut, const float* __restrict__ fbOut)
{
    __shared__ float WfInT[4096];    // [col][k-swizzled]
    __shared__ float WfMidT[4096];
    __shared__ float WfOut0T[4096];  // col j holds WfOut[k][2j]
    __shared__ float WfOut1T[4096];  // col j holds WfOut[k][2j+1]
    __shared__ float4 bufA[4][16];
    __shared__ float4 bufB[4][16];
    int tid = threadIdx.x;
    int wv = tid >> 6;
    int lane = tid & 63;
    int bn = blockIdx.x*4 + wv;            // (b*307+n) in [0,4912)
    int base = bn*64 + lane;

    // one-time weight stage: transpose + seg-swizzle
    for (int e = tid; e < 4096; e += 256){
        int c = e >> 6, k = e & 63;
        int kp = (((k >> 2) ^ (c & 15)) << 2) | (k & 3);
        WfInT [c*64 + kp] = WfIn [k*64 + c];
        WfMidT[c*64 + kp] = WfMid[k*64 + c];
    }
    for (int e = tid; e < 8192; e += 256){
        int k = e >> 7, c2 = e & 127;
        int j = c2 >> 1;
        int kp = (((k >> 2) ^ (j & 15)) << 2) | (k & 3);
        float v = WfOut[e];
        if (c2 & 1) WfOut1T[j*64 + kp] = v;
        else        WfOut0T[j*64 + kp] = v;
    }
    __syncthreads();

    const int lsw = lane & 15;
    float hv = h0[base];
    float acch = 0.f, khprev = 0.f;

#pragma unroll 1
    for (int stage = 0; stage < 44; stage++){
        int step = stage >> 2, s = stage & 3;
        float acoef = (s == 0) ? 0.f : (s == 3 ? 1.f : 0.5f);
        int idx; float frac;
        if (s == 0)        { idx = step;     frac = 0.f;  }
        else if (s < 3)    { idx = step;     frac = 0.5f; }
        else if (step < 10){ idx = step + 1; frac = 0.f;  }
        else               { idx = 10;       frac = 1.f;  }

        float sih = hv + acoef * khprev;
        ((float*)&bufA[wv][0])[lane] = sih;

        // layer 1: a0..a3 split by k mod 4, same products/order as R12
        float a0 = fbIn[lane], a1 = 0.f, a2 = 0.f, a3 = 0.f;
#pragma unroll
        for (int k4 = 0; k4 < 16; k4 += 2){
            float4 s4 = bufA[wv][k4];
            float4 s5 = bufA[wv][k4+1];
            float4 w4 = *(const float4*)(WfInT + lane*64 + (((k4)   ^ lsw) << 2));
            float4 w5 = *(const float4*)(WfInT + lane*64 + (((k4+1) ^ lsw) << 2));
            a0 += s4.x*w4.x;
            a1 += s4.y*w4.y;
            a2 += s4.z*w4.z;
            a3 += s4.w*w4.w;
            a0 += s5.x*w5.x;
            a1 += s5.y*w5.y;
            a2 += s5.z*w5.z;
            a3 += s5.w*w5.w;
        }
        float u = fmaxf((a0 + a1) + (a2 + a3), 0.f);
        ((float*)&bufB[wv][0])[lane] = u;

        // layer 2
        float c0_ = fbMid[lane], c1_ = 0.f, c2_ = 0.f, c3_ = 0.f;
#pragma unroll
        for (int k4 = 0; k4 < 16; k4 += 2){
            float4 s4 = bufB[wv][k4];
            float4 s5 = bufB[wv][k4+1];
            float4 w4 = *(const float4*)(WfMidT + lane*64 + (((k4)   ^ lsw) << 2));
            float4 w5 = *(const float4*)(WfMidT + lane*64 + (((k4+1) ^ lsw) << 2));
            c0_ += s4.x*w4.x;
            c1_ += s4.y*w4.y;
            c2_ += s4.z*w4.z;
            c3_ += s4.w*w4.w;
            c0_ += s5.x*w5.x;
            c1_ += s5.y*w5.y;
            c2_ += s5.z*w5.z;
            c3_ += s5.w*w5.w;
        }
        float u2v = fmaxf((c0_ + c1_) + (c2_ + c3_), 0.f);
        ((float*)&bufA[wv][0])[lane] = u2v;

        // layer 3 (two output cols per lane)
        float f0a = fbOut[lane*2 + 0], f0b = 0.f;
        float f1a = fbOut[lane*2 + 1], f1b = 0.f;
#pragma unroll
        for (int k4 = 0; k4 < 16; k4 += 2){
            float4 s4 = bufA[wv][k4];
            float4 s5 = bufA[wv][k4+1];
            float4 p4 = *(const float4*)(WfOut0T + lane*64 + (((k4)   ^ lsw) << 2));
            float4 p5 = *(const float4*)(WfOut0T + lane*64 + (((k4+1) ^ lsw) << 2));
            float4 q4 = *(const float4*)(WfOut1T + lane*64 + (((k4)   ^ lsw) << 2));
            float4 q5 = *(const float4*)(WfOut1T + lane*64 + (((k4+1) ^ lsw) << 2));
            f0a += s4.x*p4.x; f1a += s4.x*q4.x;
            f0b += s4.y*p4.y; f1b += s4.y*q4.y;
            f0a += s4.z*p4.z; f1a += s4.z*q4.z;
            f0b += s4.w*p4.w; f1b += s4.w*q4.w;
            f0a += s5.x*p5.x; f1a += s5.x*q5.x;
            f0b += s5.y*p5.y; f1b += s5.y*q5.y;
            f0a += s5.z*p5.z; f1a += s5.z*q5.z;
            f0b += s5.w*p5.w; f1b += s5.w*q5.w;
        }
        float f0 = tanh_fast(f0a + f0b);
        float f1 = tanh_fast(f1a + f1b);

        int cb = (bn*NI + idx)*2;
        float b0 = Cb[cb], b1 = Cb[cb+1];
        float c0 = Cc[cb], c1 = Cc[cb+1];
        float d0 = Cd[cb], d1 = Cd[cb+1];
        float dx0 = b0 + (c0 + d0*frac)*frac;
        float dx1 = b1 + (c1 + d1*frac)*frac;

        float khv = f0*dx0 + f1*dx1;
        khAll[(size_t)stage*STG_STRIDE + base] = khv;
        if (s == 0)      acch = khv;
        else if (s < 3)  acch += 2.f*khv;
        else             hv = hv + (1.f/6.f)*(acch + khv);
        khprev = khv;
    }
}

// ---------- Kz1: x = relu((z + acoef*kz) @ WgIn + gbIn) -> xbf (node-major) + xT ----------
__global__ __launch_bounds__(256) void Kz1(
    const float* __restrict__ z, const float* __restrict__ kz,
    unsigned short* __restrict__ xbf, unsigned short* __restrict__ xT,
    const float* __restrict__ WgIn, const float* __restrict__ gbIn,
    int stage, float acoef)
{
    __shared__ float4 bufZ[4][16];
    int tid = threadIdx.x;
    int wv = tid >> 6;
    int lane = tid & 63;
    int bn = blockIdx.x*4 + wv;
    int base = bn*64 + lane;
    int b = (int)((unsigned)bn / 307u);
    int n = bn - b*307;

    float siz = z[base];
    if (stage > 0) siz += acoef * kz[base];
    ((float*)&bufZ[wv][0])[lane] = siz;

    float xa = gbIn[lane], xb = 0.f;
#pragma unroll
    for (int k4 = 0; k4 < 16; k4 += 2){
        float4 z4 = bufZ[wv][k4];
        float4 z5 = bufZ[wv][k4+1];
        int k = k4*4;
        xa += z4.x*WgIn[(k+0)*64 + lane];
        xb += z4.y*WgIn[(k+1)*64 + lane];
        xa += z4.z*WgIn[(k+2)*64 + lane];
        xb += z4.w*WgIn[(k+3)*64 + lane];
        xa += z5.x*WgIn[(k+4)*64 + lane];
        xb += z5.y*WgIn[(k+5)*64 + lane];
        xa += z5.z*WgIn[(k+6)*64 + lane];
        xb += z5.w*WgIn[(k+7)*64 + lane];
    }
    unsigned short xbfv = f2bf(fmaxf(xa + xb, 0.f));
    xbf[((size_t)n*16 + b)*64 + lane] = xbfv;
    xT[((size_t)b*64 + lane)*320 + n] = xbfv;
}

// ---------- KXG: xg = A @ x per batch, pure-MFMA, no LDS. grid 320 ----------
__global__ __launch_bounds__(256) void KXG(
    const unsigned short* __restrict__ xT, const unsigned short* __restrict__ Abf,
    unsigned short* __restrict__ xgbf)
{
    int tid = threadIdx.x, lane = tid & 63, wv = tid >> 6;
    int quad = lane >> 4, l15 = lane & 15;
    int b = blockIdx.x / 20, nt = blockIdx.x % 20;
    int n0 = nt*16;

    f32x4 acc = {0.f,0.f,0.f,0.f};
#pragma unroll
    for (int mt = 0; mt < 10; mt++){
        bf16x8 a  = *(const bf16x8*)(Abf + (size_t)(n0 + l15)*320 + mt*32 + quad*8);
        bf16x8 bb = *(const bf16x8*)(xT + ((size_t)b*64 + wv*16 + l15)*320 + mt*32 + quad*8);
        acc = __builtin_amdgcn_mfma_f32_16x16x32_bf16(a, bb, acc, 0, 0, 0);
    }
#pragma unroll
    for (int r = 0; r < 4; r++){
        int n = n0 + quad*4 + r;
        xgbf[((size_t)n*16 + b)*64 + wv*16 + l15] = f2bf(acc[r]);
    }
}

// ---------- K2f: fused Y-compute + DMA-staged Wt GEMM + tanh*kh + RK4 z ----------
__global__ __launch_bounds__(256, 3) void K2f(
    float* __restrict__ z, const float* __restrict__ khS,
    float* __restrict__ kz, float* __restrict__ accz,
    const unsigned short* __restrict__ xbf, const unsigned short* __restrict__ xgbf,
    const unsigned short* __restrict__ agcWt, const float* __restrict__ agcb,
    const unsigned short* __restrict__ Wt_sw, const float* __restrict__ gbOut,
    int stage)
{
    __shared__ unsigned short WtL[256*64];
    __shared__ unsigned short Ybf[64*68];
    __shared__ float dzl[4*16*5];
    int tid = threadIdx.x, lane = tid & 63, wv = tid >> 6;
    int quad = lane >> 4, l15 = lane & 15;
    int nt = blockIdx.x >> 4, cg = blockIdx.x & 15;
    int n0 = nt*4;
    int nw = n0 + wv;
    int n = nw < NN ? nw : NN-1;
    int C0 = cg*256;

#pragma unroll
    for (int it = 0; it < 8; it++){
        int seg = it*256 + wv*64 + lane;
        const unsigned short* src = Wt_sw + (size_t)C0*64 + (size_t)seg*8;
        __builtin_amdgcn_global_load_lds(
            (const __attribute__((address_space(1))) void*)src,
            (__attribute__((address_space(3))) void*)(WtL + (it*256 + wv*64)*8),
            16, 0, 0);
    }

    float4 khr[4];
#pragma unroll
    for (int c = 0; c < 4; c++)
        khr[c] = *(const float4*)(khS + ((size_t)l15*NN + n)*64 + c*16 + quad*4);

    {
        const size_t xrow = ((size_t)n*16 + l15)*64;
        bf16x8 a[4];
        a[0] = *(const bf16x8*)(xbf  + xrow + 0  + quad*8);
        a[1] = *(const bf16x8*)(xbf  + xrow + 32 + quad*8);
        a[2] = *(const bf16x8*)(xgbf + xrow + 0  + quad*8);
        a[3] = *(const bf16x8*)(xgbf + xrow + 32 + quad*8);
#pragma unroll
        for (int ot = 0; ot < 4; ot++){
            f32x4 acc = {0.f,0.f,0.f,0.f};
#pragma unroll
            for (int kt = 0; kt < 4; kt++){
                bf16x8 bbb = *(const bf16x8*)(agcWt + ((size_t)n*64 + ot*16 + l15)*128 + kt*32 + quad*8);
                acc = __builtin_amdgcn_mfma_f32_16x16x32_bf16(a[kt], bbb, acc, 0, 0, 0);
            }
            float gb = agcb[n*64 + ot*16 + l15];
#pragma unroll
            for (int r = 0; r < 4; r++)
                Ybf[(wv*16 + quad*4 + r)*68 + ot*16 + l15] = f2bf(fmaxf(acc[r] + gb, 0.f));
        }
    }

    __syncthreads();

    bf16x8 bb0 = *(const bf16x8*)(Ybf + (wv*16 + l15)*68 + 0  + quad*8);
    bf16x8 bb1 = *(const bf16x8*)(Ybf + (wv*16 + l15)*68 + 32 + quad*8);

    int sw = l15 & 7;
#pragma unroll
    for (int i4 = 0; i4 < 4; i4++){
        float pacc = 0.f;
#pragma unroll
        for (int c4 = 0; c4 < 4; c4++){
            int ct = i4*4 + c4;
            int row = ct*16 + l15;
            f32x4 acc = {0.f,0.f,0.f,0.f};
            bf16x8 a0 = *(const bf16x8*)(WtL + row*64 + (((quad)     ^ sw) << 3));
            acc = __builtin_amdgcn_mfma_f32_16x16x32_bf16(a0, bb0, acc, 0, 0, 0);
            bf16x8 a1 = *(const bf16x8*)(WtL + row*64 + (((4 + quad) ^ sw) << 3));
            acc = __builtin_amdgcn_mfma_f32_16x16x32_bf16(a1, bb1, acc, 0, 0, 0);
            float4 gb4 = *(const float4*)(gbOut + C0 + ct*16 + quad*4);
            float4 kh4 = khr[c4];
            pacc += tanh_fast(acc[0] + gb4.x) * kh4.x
                  + tanh_fast(acc[1] + gb4.y) * kh4.y
                  + tanh_fast(acc[2] + gb4.z) * kh4.z
                  + tanh_fast(acc[3] + gb4.w) * kh4.w;
        }
        pacc += __shfl_xor(pacc, 16, 64);
        pacc += __shfl_xor(pacc, 32, 64);
        if (quad == 0) dzl[(wv*16 + l15)*5 + i4] = pacc;
    }

    {
        int w = tid >> 6, bb_ = (tid >> 2) & 15, il = tid & 3;
        int nn = n0 + w;
        if (nn < NN){
            size_t addr = ((size_t)bb_*NN + nn)*64 + cg*4 + il;
            float v = dzl[(w*16 + bb_)*5 + il];
            kz[addr] = v;
            if (stage == 0)      accz[addr] = v;
            else if (stage < 3)  accz[addr] += 2.f*v;
            else                 z[addr] += (1.f/6.f)*(accz[addr] + v);
        }
    }
}

// ---------- output ----------
__global__ __launch_bounds__(256) void kOut(const float* __restrict__ z,
                                            const float* __restrict__ convW,
                                            const float* __restrict__ convB,
                                            float* __restrict__ out){
    int gid = blockIdx.x*256 + threadIdx.x;
    if (gid >= NB*NN) return;
    int b = gid / NN, n = gid % NN;
    float zr[64];
    const float4* zp = (const float4*)(z + (size_t)gid*64);
#pragma unroll
    for (int k4 = 0; k4 < 16; k4++){
        float4 v = zp[k4];
        zr[k4*4+0] = v.x; zr[k4*4+1] = v.y; zr[k4*4+2] = v.z; zr[k4*4+3] = v.w;
    }
#pragma unroll
    for (int o = 0; o < 12; o++){
        float acc = convB[o];
#pragma unroll
        for (int hh = 0; hh < 64; hh++) acc += zr[hh]*convW[o*64 + hh];
        out[(b*12 + o)*NN + n] = acc;
    }
}

extern "C" void kernel_launch(void* const* d_in, const int* in_sizes, int n_in,
                              void* d_out, int out_size, void* d_ws, size_t ws_size,
                              hipStream_t stream)
{
    const float* coeff_a = (const float*)d_in[0];
    const float* coeff_b = (const float*)d_in[1];
    const float* coeff_c = (const float*)d_in[2];
    const float* coeff_d = (const float*)d_in[3];
    const float* hW     = (const float*)d_in[5];
    const float* hb     = (const float*)d_in[6];
    const float* zW     = (const float*)d_in[7];
    const float* zb     = (const float*)d_in[8];
    const float* WfIn   = (const float*)d_in[9];
    const float* fbIn   = (const float*)d_in[10];
    const float* WfMid  = (const float*)d_in[11];
    const float* fbMid  = (const float*)d_in[12];
    const float* WfOut  = (const float*)d_in[13];
    const float* fbOut  = (const float*)d_in[14];
    const float* WgIn   = (const float*)d_in[15];
    const float* gbIn   = (const float*)d_in[16];
    const float* gE     = (const float*)d_in[17];
    const float* gWpool = (const float*)d_in[18];
    const float* gbpool = (const float*)d_in[19];
    const float* WgOut  = (const float*)d_in[20];
    const float* gbOut  = (const float*)d_in[21];
    const float* convW  = (const float*)d_in[22];
    const float* convB  = (const float*)d_in[23];

    float* ws = (float*)d_ws;
    unsigned short* Abf   = (unsigned short*)(ws + OFF_ABF);
    unsigned short* agcWt = (unsigned short*)(ws + OFF_AGCWT);
    float*          agcb  = ws + OFF_AGCB;
    unsigned short* Wt_sw = (unsigned short*)(ws + OFF_WT);
    float* h     = ws + OFF_H;
    float* z     = ws + OFF_Z;
    float* kz    = ws + OFF_KZ;
    float* accz  = ws + OFF_ACCZ;
    unsigned short* xbf  = (unsigned short*)(ws + OFF_XBF);
    unsigned short* xgbf = (unsigned short*)(ws + OFF_XGBF);
    unsigned short* xT   = (unsigned short*)(ws + OFF_XT);
    float* khAll = ws + OFF_KHALL;
    float* out = (float*)d_out;

    kA        <<<320, 64,  0, stream>>>(gE, Abf);
    kAgcWT    <<<NN,  256, 0, stream>>>(gE, gWpool, agcWt);
    kAgcB     <<<77,  256, 0, stream>>>(gE, gbpool, agcb);
    kWt       <<<64,  256, 0, stream>>>(WgOut, Wt_sw);
    kZeroTail <<<64,  256, 0, stream>>>(xT);
    kInit     <<<1228,256, 0, stream>>>(coeff_a, hW, hb, zW, zb, h, z);

    // one launch: full h-ODE, all 44 stage kh slabs (transposed LDS weights)
    KH<<<1228, 256, 0, stream>>>(h, khAll, coeff_b, coeff_c, coeff_d,
                                 WfIn, fbIn, WfMid, fbMid, WfOut, fbOut);

    const float acoef[4] = {0.f, 0.5f, 0.5f, 1.f};
    for (int step = 0; step < 11; step++){
        for (int s = 0; s < 4; s++){
            const float* khS = khAll + (size_t)(step*4 + s)*STG_STRIDE;
            Kz1<<<1228, 256, 0, stream>>>(z, kz, xbf, xT, WgIn, gbIn, s, acoef[s]);
            KXG<<<320, 256, 0, stream>>>(xT, Abf, xgbf);
            K2f<<<1232, 256, 0, stream>>>(z, khS, kz, accz, xbf, xgbf,
                                          agcWt, agcb, Wt_sw, gbOut, s);
        }
    }
    kOut<<<20, 256, 0, stream>>>(z, convW, convB, out);
}